// Round 13
// baseline (1835.333 us; speedup 1.0000x reference)
//
#include <hip/hip_runtime.h>
#include <cstdint>
#include <cstddef>

typedef __bf16 bf;
typedef __attribute__((ext_vector_type(8))) __bf16 bf16x8;
typedef __attribute__((ext_vector_type(4))) float f32x4;
typedef __attribute__((ext_vector_type(16))) float f32x16;
typedef long long ll;

#define DEV __device__ __forceinline__

// ---- problem constants ----
constexpr int Tt = 576;
constexpr int NHh = 8;
constexpr float EPSf = 1e-6f;
constexpr float SCALEf = 0.0625f;          // HD^-0.5 = 1/16
constexpr float LN1E4_OVER_128 = 0.07195578515606394f; // ln(10000)/128

constexpr int EPI_F32 = 0, EPI_SCALE_BF16 = 1, EPI_BF16 = 2, EPI_GELU_BF16 = 3,
              EPI_MUL_BF16 = 4, EPI_RES_F32 = 5, EPI_RESGATE_F32 = 6;

DEV float wsum(float v) {
#pragma unroll
  for (int o = 32; o > 0; o >>= 1) v += __shfl_xor(v, o, 64);
  return v;
}
DEV float wmaxr(float v) {
#pragma unroll
  for (int o = 32; o > 0; o >>= 1) v = fmaxf(v, __shfl_xor(v, o, 64));
  return v;
}
DEV float gelu_tanh(float x) {
  float x3 = x * x * x;
  float t = tanhf(0.7978845608028654f * (x + 0.044715f * x3));
  return 0.5f * x * (1.0f + t);
}

// async global->LDS, 16B per lane, wave-uniform LDS base + lane*16 (m97 pattern)
DEV void gld16(const void* g, void* l) {
  __builtin_amdgcn_global_load_lds(
      (__attribute__((address_space(1))) void*)(g),
      (__attribute__((address_space(3))) void*)(l), 16, 0, 0);
}

// ---------------- small kernels ----------------

// batched fp32->bf16 conversion of all 14 weight matrices (contiguous bf16 dst)
struct CvtArgs {
  const float* src[14];
  ll cum8[15];     // vec8 prefix offsets
  bf* dst;         // contiguous destination base
};

__global__ void f2b_all(CvtArgs a, int totN8) {
  int i = blockIdx.x * 256 + threadIdx.x;
  int stride = gridDim.x * 256;
  for (; i < totN8; i += stride) {
    int s = 0;
#pragma unroll
    for (int j = 1; j < 14; j++) if (i >= a.cum8[j]) s = j;
    const float* sp = a.src[s] + ((ll)i - a.cum8[s]) * 8;
    f32x4 v0 = *(const f32x4*)sp;
    f32x4 v1 = *(const f32x4*)(sp + 4);
    bf16x8 w;
    w[0] = (bf)v0[0]; w[1] = (bf)v0[1]; w[2] = (bf)v0[2]; w[3] = (bf)v0[3];
    w[4] = (bf)v1[0]; w[5] = (bf)v1[1]; w[6] = (bf)v1[2]; w[7] = (bf)v1[3];
    ((bf16x8*)a.dst)[i] = w;
  }
}

__global__ void rms_scale_2048(const float* __restrict__ x, const float* __restrict__ w,
                               bf* __restrict__ out) {
  int row = blockIdx.x;
  int tid = threadIdx.x;
  const float* xr = x + (ll)row * 2048;
  f32x4 a = *(const f32x4*)(xr + tid * 4);
  f32x4 b = *(const f32x4*)(xr + 1024 + tid * 4);
  float ss = a[0]*a[0]+a[1]*a[1]+a[2]*a[2]+a[3]*a[3]
           + b[0]*b[0]+b[1]*b[1]+b[2]*b[2]+b[3]*b[3];
  ss = wsum(ss);
  __shared__ float red[4];
  if ((tid & 63) == 0) red[tid >> 6] = ss;
  __syncthreads();
  float tot = red[0] + red[1] + red[2] + red[3];
  float sc = rsqrtf(tot * (1.0f / 2048.0f) + EPSf);
  bf* o = out + (ll)row * 2048;
#pragma unroll
  for (int j = 0; j < 4; j++) {
    int c0 = tid * 4 + j;
    o[c0]        = (bf)(a[j] * sc * (1.0f + w[c0]));
    o[1024 + c0] = (bf)(b[j] * sc * (1.0f + w[1024 + c0]));
  }
}

__global__ void ada_mod_k(const float* __restrict__ cond, const float* __restrict__ w,
                          const float* __restrict__ bias, float* __restrict__ mod) {
  int n = blockIdx.x * 256 + threadIdx.x;
  int b = blockIdx.y;
  const float* c = cond + b * 1024;
  const float* wr = w + (ll)n * 1024;
  float s = 0.f;
  for (int k = 0; k < 1024; k += 4) {
    f32x4 cv = *(const f32x4*)(c + k);
    f32x4 wv = *(const f32x4*)(wr + k);
    s += cv[0]*wv[0] + cv[1]*wv[1] + cv[2]*wv[2] + cv[3]*wv[3];
  }
  mod[b * 3072 + n] = s + bias[n];
}

__global__ void ada_norm_k(const float* __restrict__ x, const float* __restrict__ mod,
                           bf* __restrict__ out) {
  int row = blockIdx.x;
  int b = row >> 6;
  int tid = threadIdx.x;
  const float* xr = x + (ll)row * 1024;
  f32x4 a = *(const f32x4*)(xr + tid * 4);
  float ss = a[0]*a[0] + a[1]*a[1] + a[2]*a[2] + a[3]*a[3];
  ss = wsum(ss);
  __shared__ float red[4];
  if ((tid & 63) == 0) red[tid >> 6] = ss;
  __syncthreads();
  float tot = red[0] + red[1] + red[2] + red[3];
  float sc = rsqrtf(tot * (1.0f / 1024.0f) + EPSf);
  const float* m = mod + b * 3072;
  bf* o = out + (ll)row * 1024;
#pragma unroll
  for (int j = 0; j < 4; j++) {
    int c = tid * 4 + j;
    o[c] = (bf)(a[j] * sc * (1.0f + m[c]) + m[1024 + c]);
  }
}

// RoPE from fused qkv buffer (B,T,2560): q cols 0-2047, k 2048-2303, v 2304-2559
__global__ void rope_k(const float* __restrict__ qkv,
                       const int* __restrict__ pos, bf* __restrict__ qb,
                       bf* __restrict__ kb, bf* __restrict__ vT) {
  int bt = blockIdx.x;
  int b = bt / Tt, t = bt - b * Tt;
  int tid = threadIdx.x;
  float p = (float)pos[bt];
  const float* qr = qkv + (ll)bt * 2560;
#pragma unroll
  for (int j = 0; j < 4; j++) {
    int pi = tid + 256 * j;       // 0..1023
    int h = pi >> 7, d = pi & 127;
    float ang = p * expf((float)d * (-LN1E4_OVER_128));
    float sn = sinf(ang), cs = cosf(ang);
    float x1 = qr[h * 256 + d], x2 = qr[h * 256 + d + 128];
    bf* qo = qb + ((ll)(b * NHh + h) * Tt + t) * 256;
    qo[d]       = (bf)(x1 * cs - x2 * sn);
    qo[d + 128] = (bf)(x2 * cs + x1 * sn);
  }
  const float* kvr = qr + 2048;
  if (tid < 128) {
    int d = tid;
    float ang = p * expf((float)d * (-LN1E4_OVER_128));
    float sn = sinf(ang), cs = cosf(ang);
    float x1 = kvr[d], x2 = kvr[d + 128];
    bf* ko = kb + (ll)bt * 256;
    ko[d]       = (bf)(x1 * cs - x2 * sn);
    ko[d + 128] = (bf)(x2 * cs + x1 * sn);
  } else {
    int d = tid - 128;
    const float* vv = kvr + 256;
    vT[((ll)b * 256 + d) * Tt + t]       = (bf)vv[d];
    vT[((ll)b * 256 + d + 128) * Tt + t] = (bf)vv[d + 128];
  }
}

__global__ void softmax_k(const bf* __restrict__ scores, const float* __restrict__ mask,
                          bf* __restrict__ probs) {
  int rowg = blockIdx.x * 4 + (threadIdx.x >> 6);
  int lane = threadIdx.x & 63;
  int z = rowg / Tt;       // b*NH+h
  int t = rowg - z * Tt;
  int b = z >> 3;
  const bf* s = scores + (ll)rowg * Tt;
  const float* mr = mask + ((ll)b * Tt + t) * Tt;
  float v[9];
#pragma unroll
  for (int j = 0; j < 9; j++) {
    int c = lane + j * 64;
    v[j] = (float)s[c] + mr[c];
  }
  float mx = v[0];
#pragma unroll
  for (int j = 1; j < 9; j++) mx = fmaxf(mx, v[j]);
  mx = wmaxr(mx);
  float sum = 0.f;
#pragma unroll
  for (int j = 0; j < 9; j++) { v[j] = __expf(v[j] - mx); sum += v[j]; }
  sum = wsum(sum);
  float inv = 1.0f / sum;
  bf* pr = probs + (ll)rowg * Tt;
#pragma unroll
  for (int j = 0; j < 9; j++) pr[lane + j * 64] = (bf)(v[j] * inv);
}

// ---------------- GEMM: C = A (bf16, MxK) * B^T ----------------

struct GemmArgs {
  const bf* A; ll sA; int lda;
  const void* Bp; ll sB; int ldb; int zdivB;
  void* C; ll sC; ll sC2; int zdivC; int ldc;
  int M, N, K;
  const float* res; ll sRes;
  const float* gate; ll sGate;
  const bf* aux; ll sAux;
  float alpha;
};

template <int EPI>
DEV void epilogue(const GemmArgs& g, f32x4 (&acc)[4][4], int z, int m0, int n0,
                  int lane, int wr, int wc) {
  const ll coff = (ll)(z / g.zdivC) * g.sC + (ll)(z % g.zdivC) * g.sC2;
  const int r0 = (lane >> 4) * 4;
  const int cc = lane & 15;
#pragma unroll
  for (int m = 0; m < 4; m++) {
#pragma unroll
    for (int n = 0; n < 4; n++) {
      int col = n0 + wc * 64 + n * 16 + cc;
      if (col >= g.N) continue;
#pragma unroll
      for (int r = 0; r < 4; r++) {
        int row = m0 + wr * 64 + m * 16 + r0 + r;
        if (row >= g.M) continue;
        float v = acc[m][n][r];
        ll idx = (ll)row * g.ldc + col;
        if constexpr (EPI == EPI_F32) {
          ((float*)g.C)[coff + idx] = v;
        } else if constexpr (EPI == EPI_SCALE_BF16) {
          ((bf*)g.C)[coff + idx] = (bf)(v * g.alpha);
        } else if constexpr (EPI == EPI_BF16) {
          ((bf*)g.C)[coff + idx] = (bf)v;
        } else if constexpr (EPI == EPI_GELU_BF16) {
          ((bf*)g.C)[coff + idx] = (bf)gelu_tanh(v);
        } else if constexpr (EPI == EPI_MUL_BF16) {
          float a0 = (float)g.aux[(ll)z * g.sAux + idx];
          ((bf*)g.C)[coff + idx] = (bf)(a0 * v);
        } else if constexpr (EPI == EPI_RES_F32) {
          ((float*)g.C)[coff + idx] = g.res[(ll)z * g.sRes + idx] + v;
        } else if constexpr (EPI == EPI_RESGATE_F32) {
          ((float*)g.C)[coff + idx] =
              g.res[(ll)z * g.sRes + idx] + v * g.gate[(ll)z * g.sGate + col];
        }
      }
    }
  }
}

// ======== 8-phase 256xBN GEMM (r12 schedule, 32x32x16 MFMA fragments) ========
// Wave tile 128 x WN; per phase one 32-row M-frag; K=16 slices x4 per tile.
// A-frag: row = lane&31, k = (lane>>5)*8 + [0..7]; C/D: col = lane&31,
// row = (reg&3) + 8*(reg>>2) + 4*(lane>>5)  [HW-verified m74/m101].
template <int EPI, int BN>
__global__ __launch_bounds__(512) void gemm_8p(GemmArgs g) {
  constexpr int NF = BN / 128;           // 32-wide B-frags per wave (1 or 2)
  constexpr int WN = BN / 4;             // wave col span (32 or 64)
  const int z = blockIdx.z;
  const int m0 = blockIdx.x * 256;
  const int n0 = blockIdx.y * BN;
  const int tid = threadIdx.x;
  const int lane = tid & 63;
  const int wv = tid >> 6;               // 0..7
  const int wr = wv >> 2;                // 0..1 (M half)
  const int wc = wv & 3;                 // 0..3 (N quarter)

  const bf* A = g.A + (ll)z * g.sA;
  const bf* B = (const bf*)g.Bp + (ll)(z / g.zdivB) * g.sB;

  __shared__ __align__(16) bf lA[2][256 * 64];
  __shared__ __align__(16) bf lB[2][BN * 64];

  f32x16 acc[4][NF];
#pragma unroll
  for (int m = 0; m < 4; m++)
#pragma unroll
    for (int n = 0; n < NF; n++)
#pragma unroll
      for (int j = 0; j < 16; j++) acc[m][n][j] = 0.f;

  const int lrow = lane >> 3;                  // 0..7
  const int lsrc = ((lane & 7) ^ lrow) * 8;    // T2 swizzled source col

  auto stage128 = [&](const bf* src, int ld, int grow0, bf* lds) {
#pragma unroll
    for (int i = 0; i < 2; i++) {
      int chunk = wv * 2 + i;                  // wave-uniform base
      gld16(src + (ll)(grow0 + chunk * 8 + lrow) * ld + lsrc, lds + chunk * 512);
    }
  };

  const int NT = g.K >> 6;
  stage128(B, g.ldb, n0, &lB[0][0]);
  if (BN == 256) stage128(B, g.ldb, n0 + 128, &lB[0][128 * 64]);
  stage128(A, g.lda, m0, &lA[0][0]);
  stage128(A, g.lda, m0 + 128, &lA[0][128 * 64]);
  asm volatile("s_waitcnt vmcnt(0)" ::: "memory");
  __builtin_amdgcn_s_barrier();

  const int kg = (lane >> 5) * 8;              // k-group offset within K=16

  for (int t = 0; t < NT; ++t) {
    const int c = t & 1;
    const int nx = (t + 1 < NT) ? t + 1 : t;
    const ll kkn = (ll)nx * 64;
    bf16x8 bv[NF][4];
#pragma unroll
    for (int p = 0; p < 4; ++p) {
      if (p == 0) {
#pragma unroll
        for (int n = 0; n < NF; ++n)
#pragma unroll
          for (int ks = 0; ks < 4; ++ks) {
            int row = wc * WN + n * 32 + (lane & 31);
            int ko = ks * 16 + kg;
            bv[n][ks] = *(const bf16x8*)&lB[c][row * 64 + (ko ^ ((row & 7) * 8))];
          }
      }
      bf16x8 af[4];
#pragma unroll
      for (int ks = 0; ks < 4; ++ks) {
        int row = wr * 128 + p * 32 + (lane & 31);
        int ko = ks * 16 + kg;
        af[ks] = *(const bf16x8*)&lA[c][row * 64 + (ko ^ ((row & 7) * 8))];
      }
      if (p == 0) {                              // B(t+1) at p0
        stage128(B + kkn, g.ldb, n0, &lB[1 - c][0]);
        if (BN == 256) stage128(B + kkn, g.ldb, n0 + 128, &lB[1 - c][128 * 64]);
      } else if (p == 1) {                       // A(t+1) at p1
        stage128(A + kkn, g.lda, m0, &lA[1 - c][0]);
        stage128(A + kkn, g.lda, m0 + 128, &lA[1 - c][128 * 64]);
      }
      __builtin_amdgcn_s_barrier();
      asm volatile("s_waitcnt lgkmcnt(0)" ::: "memory");
      __builtin_amdgcn_s_setprio(1);
#pragma unroll
      for (int ks = 0; ks < 4; ++ks)
#pragma unroll
        for (int n = 0; n < NF; ++n)
          acc[p][n] = __builtin_amdgcn_mfma_f32_32x32x16_bf16(
              af[ks], bv[n][ks], acc[p][n], 0, 0, 0);
      __builtin_amdgcn_s_setprio(0);
      if (p == 3) asm volatile("s_waitcnt vmcnt(0)" ::: "memory");
      __builtin_amdgcn_s_barrier();
    }
  }

  const ll coff = (ll)(z / g.zdivC) * g.sC + (ll)(z % g.zdivC) * g.sC2;
  const int rbase = (lane >> 5) * 4;
  const int cc = lane & 31;
#pragma unroll
  for (int m = 0; m < 4; m++) {
#pragma unroll
    for (int n = 0; n < NF; n++) {
      int col = n0 + wc * WN + n * 32 + cc;
#pragma unroll
      for (int r = 0; r < 16; r++) {
        int row = m0 + wr * 128 + m * 32 + (r & 3) + 8 * (r >> 2) + rbase;
        float v = acc[m][n][r];
        ll idx = (ll)row * g.ldc + col;
        if constexpr (EPI == EPI_F32) {
          ((float*)g.C)[coff + idx] = v;
        } else if constexpr (EPI == EPI_GELU_BF16) {
          ((bf*)g.C)[coff + idx] = (bf)gelu_tanh(v);
        } else if constexpr (EPI == EPI_MUL_BF16) {
          float a0 = (float)g.aux[(ll)z * g.sAux + idx];
          ((bf*)g.C)[coff + idx] = (bf)(a0 * v);
        } else if constexpr (EPI == EPI_RES_F32) {
          ((float*)g.C)[coff + idx] = g.res[(ll)z * g.sRes + idx] + v;
        }
      }
    }
  }
}

// ======== fused dual-B 8-phase MLP kernel (r12 schedule, 32x32x16 MFMA) ========
// C = gelu(A@B1^T) * (A@B2^T). BM=256, BN=128. LDS = 64 + 32 + 32 = 128 KB.
struct FusedArgs {
  const bf* A; int lda;
  const bf* B1; const bf* B2; int ldb;
  bf* C; int ldc;
  int K;
};

__global__ __launch_bounds__(512) void gemm_8pf(FusedArgs g) {
  const int m0 = blockIdx.x * 256;
  const int n0 = blockIdx.y * 128;
  const int tid = threadIdx.x;
  const int lane = tid & 63;
  const int wv = tid >> 6;
  const int wr = wv >> 2;
  const int wc = wv & 3;

  __shared__ __align__(16) bf lA[2][256 * 64];
  __shared__ __align__(16) bf lB1[2][128 * 64];
  __shared__ __align__(16) bf lB2[2][128 * 64];

  f32x16 acc1[4], acc2[4];
#pragma unroll
  for (int m = 0; m < 4; m++)
#pragma unroll
    for (int j = 0; j < 16; j++) { acc1[m][j] = 0.f; acc2[m][j] = 0.f; }

  const int lrow = lane >> 3;
  const int lsrc = ((lane & 7) ^ lrow) * 8;

  auto stage128 = [&](const bf* src, int ld, int grow0, bf* lds) {
#pragma unroll
    for (int i = 0; i < 2; i++) {
      int chunk = wv * 2 + i;
      gld16(src + (ll)(grow0 + chunk * 8 + lrow) * ld + lsrc, lds + chunk * 512);
    }
  };

  const int NT = g.K >> 6;
  stage128(g.B1, g.ldb, n0, &lB1[0][0]);
  stage128(g.B2, g.ldb, n0, &lB2[0][0]);
  stage128(g.A, g.lda, m0, &lA[0][0]);
  stage128(g.A, g.lda, m0 + 128, &lA[0][128 * 64]);
  asm volatile("s_waitcnt vmcnt(0)" ::: "memory");
  __builtin_amdgcn_s_barrier();

  const int kg = (lane >> 5) * 8;

  for (int t = 0; t < NT; ++t) {
    const int c = t & 1;
    const int nx = (t + 1 < NT) ? t + 1 : t;
    const ll kkn = (ll)nx * 64;
    bf16x8 b1v[4], b2v[4];
#pragma unroll
    for (int p = 0; p < 4; ++p) {
      if (p == 0) {
#pragma unroll
        for (int ks = 0; ks < 4; ++ks) {
          int row = wc * 32 + (lane & 31);
          int ko = ks * 16 + kg;
          int sw = row * 64 + (ko ^ ((row & 7) * 8));
          b1v[ks] = *(const bf16x8*)&lB1[c][sw];
          b2v[ks] = *(const bf16x8*)&lB2[c][sw];
        }
      }
      bf16x8 af[4];
#pragma unroll
      for (int ks = 0; ks < 4; ++ks) {
        int row = wr * 128 + p * 32 + (lane & 31);
        int ko = ks * 16 + kg;
        af[ks] = *(const bf16x8*)&lA[c][row * 64 + (ko ^ ((row & 7) * 8))];
      }
      if (p == 0) {                              // B1,B2(t+1) at p0
        stage128(g.B1 + kkn, g.ldb, n0, &lB1[1 - c][0]);
        stage128(g.B2 + kkn, g.ldb, n0, &lB2[1 - c][0]);
      } else if (p == 1) {                       // A(t+1) at p1
        stage128(g.A + kkn, g.lda, m0, &lA[1 - c][0]);
        stage128(g.A + kkn, g.lda, m0 + 128, &lA[1 - c][128 * 64]);
      }
      __builtin_amdgcn_s_barrier();
      asm volatile("s_waitcnt lgkmcnt(0)" ::: "memory");
      __builtin_amdgcn_s_setprio(1);
#pragma unroll
      for (int ks = 0; ks < 4; ++ks) {
        acc1[p] = __builtin_amdgcn_mfma_f32_32x32x16_bf16(af[ks], b1v[ks], acc1[p], 0, 0, 0);
        acc2[p] = __builtin_amdgcn_mfma_f32_32x32x16_bf16(af[ks], b2v[ks], acc2[p], 0, 0, 0);
      }
      __builtin_amdgcn_s_setprio(0);
      if (p == 3) asm volatile("s_waitcnt vmcnt(0)" ::: "memory");
      __builtin_amdgcn_s_barrier();
    }
  }

  const int rbase = (lane >> 5) * 4;
  const int cc = lane & 31;
#pragma unroll
  for (int m = 0; m < 4; m++) {
    int col = n0 + wc * 32 + cc;
#pragma unroll
    for (int r = 0; r < 16; r++) {
      int row = m0 + wr * 128 + m * 32 + (r & 3) + 8 * (r >> 2) + rbase;
      g.C[(ll)row * g.ldc + col] =
          (bf)(gelu_tanh(acc1[m][r]) * acc2[m][r]);
    }
  }
}

// Pipelined 128x128 GEMM (proven, unchanged) for small/irregular shapes.
template <int EPI>
__global__ __launch_bounds__(256) void gemm_p(GemmArgs g) {
  const int z = blockIdx.z;
  const int m0 = blockIdx.x * 128;
  const int n0 = blockIdx.y * 128;
  const int tid = threadIdx.x;
  const int lane = tid & 63;
  const int wid = tid >> 6;
  const int wr = wid >> 1, wc = wid & 1;

  const bf* A = g.A + (ll)z * g.sA;
  const bf* B = (const bf*)g.Bp + (ll)(z / g.zdivB) * g.sB;

  __shared__ __align__(16) bf lA[2][128 * 64];
  __shared__ __align__(16) bf lB[2][128 * 64];

  f32x4 acc[4][4];
  f32x4 zero = {0.f, 0.f, 0.f, 0.f};
#pragma unroll
  for (int m = 0; m < 4; m++)
#pragma unroll
    for (int n = 0; n < 4; n++) acc[m][n] = zero;

  const int lrow = lane >> 3;
  const int lsrc = ((lane & 7) ^ lrow) * 8;

  auto stage = [&](int kt, int bsel) {
    const ll kk = (ll)kt * 64;
#pragma unroll
    for (int i = 0; i < 4; i++) {
      int rr = wid * 32 + i * 8;
      int ra = m0 + rr + lrow; if (ra > g.M - 1) ra = g.M - 1;
      gld16(A + (ll)ra * g.lda + kk + lsrc, &lA[bsel][rr * 64]);
      int rb = n0 + rr + lrow; if (rb > g.N - 1) rb = g.N - 1;
      gld16(B + (ll)rb * g.ldb + kk + lsrc, &lB[bsel][rr * 64]);
    }
  };

  const int nt = g.K >> 6;
  stage(0, 0);
  stage(nt > 1 ? 1 : 0, 1);

  for (int t = 0; t < nt; ++t) {
    const int cur = t & 1;
    asm volatile("s_waitcnt vmcnt(8)" ::: "memory");
    __builtin_amdgcn_s_barrier();
    asm volatile("" ::: "memory");
#pragma unroll
    for (int kb = 0; kb < 2; kb++) {
      const int ko = kb * 32 + (lane >> 4) * 8;
      bf16x8 af[4], bv[4];
#pragma unroll
      for (int m = 0; m < 4; m++) {
        int row = wr * 64 + m * 16 + (lane & 15);
        af[m] = *(const bf16x8*)&lA[cur][row * 64 + (ko ^ ((row & 7) * 8))];
      }
#pragma unroll
      for (int n = 0; n < 4; n++) {
        int row = wc * 64 + n * 16 + (lane & 15);
        bv[n] = *(const bf16x8*)&lB[cur][row * 64 + (ko ^ ((row & 7) * 8))];
      }
      __builtin_amdgcn_s_setprio(1);
#pragma unroll
      for (int m = 0; m < 4; m++)
#pragma unroll
        for (int n = 0; n < 4; n++)
          acc[m][n] = __builtin_amdgcn_mfma_f32_16x16x32_bf16(af[m], bv[n], acc[m][n], 0, 0, 0);
      __builtin_amdgcn_s_setprio(0);
    }
    asm volatile("" ::: "memory");
    __builtin_amdgcn_s_barrier();
    asm volatile("" ::: "memory");
    int nxt = t + 2; if (nxt > nt - 1) nxt = nt - 1;
    stage(nxt, cur);
  }
  epilogue<EPI>(g, acc, z, m0, n0, lane, wr, wc);
}

// fallback: reg-staged, B fp32 converted in-flight (unchanged)
template <int EPI>
__global__ __launch_bounds__(256) void gemm_rs(GemmArgs g) {
  const int z = blockIdx.z;
  const int m0 = blockIdx.x * 128;
  const int n0 = blockIdx.y * 128;
  const int tid = threadIdx.x;
  const int lane = tid & 63;
  const int wid = tid >> 6;
  const int wr = wid >> 1, wc = wid & 1;

  const bf* A = g.A + (ll)z * g.sA;
  const float* Bf = (const float*)g.Bp + (ll)(z / g.zdivB) * g.sB;

  __shared__ __align__(16) bf lA[128 * 64];
  __shared__ __align__(16) bf lB[128 * 64];

  f32x4 acc[4][4];
  f32x4 zero = {0.f, 0.f, 0.f, 0.f};
#pragma unroll
  for (int m = 0; m < 4; m++)
#pragma unroll
    for (int n = 0; n < 4; n++) acc[m][n] = zero;

  const int srow = tid >> 3;
  const int scol = (tid & 7) * 8;

  for (int kk = 0; kk < g.K; kk += 64) {
#pragma unroll
    for (int i = 0; i < 4; i++) {
      int r = m0 + i * 32 + srow;
      if (r > g.M - 1) r = g.M - 1;
      f32x4 v = *(const f32x4*)(A + (ll)r * g.lda + kk + scol);
      *(f32x4*)&lA[(i * 32 + srow) * 64 + scol] = v;
    }
#pragma unroll
    for (int i = 0; i < 4; i++) {
      int r = n0 + i * 32 + srow;
      if (r > g.N - 1) r = g.N - 1;
      const float* src = Bf + (ll)r * g.ldb + kk + scol;
      f32x4 v0 = *(const f32x4*)(src);
      f32x4 v1 = *(const f32x4*)(src + 4);
      bf16x8 w;
      w[0] = (bf)v0[0]; w[1] = (bf)v0[1]; w[2] = (bf)v0[2]; w[3] = (bf)v0[3];
      w[4] = (bf)v1[0]; w[5] = (bf)v1[1]; w[6] = (bf)v1[2]; w[7] = (bf)v1[3];
      *(bf16x8*)&lB[(i * 32 + srow) * 64 + scol] = w;
    }
    __syncthreads();
#pragma unroll
    for (int kb = 0; kb < 2; kb++) {
      const int ko = kb * 32 + (lane >> 4) * 8;
      bf16x8 af[4], bfv[4];
#pragma unroll
      for (int m = 0; m < 4; m++)
        af[m] = *(const bf16x8*)&lA[(wr * 64 + m * 16 + (lane & 15)) * 64 + ko];
#pragma unroll
      for (int n = 0; n < 4; n++)
        bfv[n] = *(const bf16x8*)&lB[(wc * 64 + n * 16 + (lane & 15)) * 64 + ko];
#pragma unroll
      for (int m = 0; m < 4; m++)
#pragma unroll
        for (int n = 0; n < 4; n++)
          acc[m][n] = __builtin_amdgcn_mfma_f32_16x16x32_bf16(af[m], bfv[n], acc[m][n], 0, 0, 0);
    }
    __syncthreads();
  }
  epilogue<EPI>(g, acc, z, m0, n0, lane, wr, wc);
}

// ---------------- host ----------------

static GemmArgs mkG(const bf* A, ll sA, int lda, const void* Bp, ll sB, int ldb, int zdivB,
                    void* C, ll sC, ll sC2, int zdivC, int ldc, int M, int N, int K) {
  GemmArgs g{};
  g.A = A; g.sA = sA; g.lda = lda;
  g.Bp = Bp; g.sB = sB; g.ldb = ldb; g.zdivB = zdivB;
  g.C = C; g.sC = sC; g.sC2 = sC2; g.zdivC = zdivC; g.ldc = ldc;
  g.M = M; g.N = N; g.K = K;
  g.res = nullptr; g.sRes = 0; g.gate = nullptr; g.sGate = 0; g.aux = nullptr; g.sAux = 0;
  g.alpha = 1.0f;
  return g;
}

extern "C" void kernel_launch(void* const* d_in, const int* in_sizes, int n_in,
                              void* d_out, int out_size, void* d_ws, size_t ws_size,
                              hipStream_t stream) {
  (void)in_sizes; (void)n_in; (void)out_size;
  const float* x_prefix = (const float*)d_in[0];
  const float* x_suffix = (const float*)d_in[1];
  const float* cond     = (const float*)d_in[2];
  const float* mask     = (const float*)d_in[3];
  const float* p_ln1_w  = (const float*)d_in[4];
  const float* p_q      = (const float*)d_in[5];
  const float* p_k      = (const float*)d_in[6];
  const float* p_v      = (const float*)d_in[7];
  const float* p_o      = (const float*)d_in[8];
  const float* p_ln2_w  = (const float*)d_in[9];
  const float* p_gate   = (const float*)d_in[10];
  const float* p_up     = (const float*)d_in[11];
  const float* p_down   = (const float*)d_in[12];
  const float* s_ada1_w = (const float*)d_in[13];
  const float* s_ada1_b = (const float*)d_in[14];
  const float* s_q      = (const float*)d_in[15];
  const float* s_k      = (const float*)d_in[16];
  const float* s_v      = (const float*)d_in[17];
  const float* s_o      = (const float*)d_in[18];
  const float* s_ada2_w = (const float*)d_in[19];
  const float* s_ada2_b = (const float*)d_in[20];
  const float* s_gate   = (const float*)d_in[21];
  const float* s_up     = (const float*)d_in[22];
  const float* s_down   = (const float*)d_in[23];
  const int*   pos      = (const int*)d_in[24];

  char* base = (char*)d_ws;
  size_t off = 0;
  auto alloc = [&](size_t bytes) {
    char* p = base + off;
    off = (off + bytes + 255) & ~(size_t)255;
    return p;
  };
  float* qkv   = (float*)alloc(8ll * Tt * 2560 * 4);   // q|k|v fused; reused as attn (bf16)
  bf* hp     = (bf*)alloc(4096ll * 2048 * 2);          // reused as hbuf
  bf* hs     = (bf*)alloc(512ll * 1024 * 2);           // reused as h2
  float* mod1 = (float*)alloc(8 * 3072 * 4);
  float* mod2 = (float*)alloc(8 * 3072 * 4);
  bf* qb     = (bf*)alloc(64ll * Tt * 256 * 2);
  bf* kb     = (bf*)alloc(8ll * Tt * 256 * 2);
  bf* vT     = (bf*)alloc(8ll * 256 * Tt * 2);
  bf* scores = (bf*)alloc(64ll * Tt * Tt * 2);         // softmax in-place
  float* res_p = (float*)alloc(8ll * 512 * 2048 * 4);
  float* res_s = (float*)alloc(8ll * 64 * 1024 * 4);
  bf* gbuf   = (bf*)alloc(4096ll * 16384 * 2);

  bf* attn   = (bf*)qkv;
  bf* hbuf   = hp;
  bf* h2     = hs;
  bf* probs  = scores;
  bf* gbuf_s = gbuf;

  // Converted bf16 weights: 14 contiguous 256B-aligned segments (one contiguous
  // dst area). [0..2] and [7..9] form the combined QKV matrices (2560 x K).
  struct WEnt { const float* src; bf* dst; ll n; };
  WEnt went[14] = {
    {p_q,    nullptr, 2048ll * 2048}, {p_k,    nullptr, 256ll * 2048},
    {p_v,    nullptr, 256ll * 2048},  {p_o,    nullptr, 2048ll * 2048},
    {p_gate, nullptr, 16384ll * 2048},{p_up,   nullptr, 16384ll * 2048},
    {p_down, nullptr, 2048ll * 16384},{s_q,    nullptr, 2048ll * 1024},
    {s_k,    nullptr, 256ll * 1024},  {s_v,    nullptr, 256ll * 1024},
    {s_o,    nullptr, 1024ll * 2048}, {s_gate, nullptr, 4096ll * 1024},
    {s_up,   nullptr, 4096ll * 1024}, {s_down, nullptr, 1024ll * 4096},
  };
  for (int i = 0; i < 14; i++) went[i].dst = (bf*)alloc((size_t)went[i].n * 2);
  const bool conv = (off <= ws_size);

  float* outp = (float*)d_out;
  float* outs = outp + 8ll * 512 * 2048;

  dim3 blk(256);

  if (conv) {
    CvtArgs ca{};
    ll c = 0;
    for (int i = 0; i < 14; i++) { ca.src[i] = went[i].src; ca.cum8[i] = c; c += went[i].n / 8; }
    ca.cum8[14] = c;
    ca.dst = went[0].dst;
    f2b_all<<<2048, 256, 0, stream>>>(ca, (int)c);
  }
  const bf* w_pqkv = went[0].dst;                 // combined 2560x2048
  const bf* w_po = went[3].dst, *w_pg = went[4].dst, *w_pu = went[5].dst,
          *w_pd = went[6].dst;
  const bf* w_sqkv = went[7].dst;                 // combined 2560x1024
  const bf* w_so = went[10].dst, *w_sg = went[11].dst,
          *w_su = went[12].dst, *w_sd = went[13].dst;

  auto launchW = [&](int epi, GemmArgs g, const float* wf32, const bf* wbf,
                     dim3 grid) {
    if (conv) {
      g.Bp = wbf;
      switch (epi) {
        case EPI_F32:        gemm_p<EPI_F32><<<grid, blk, 0, stream>>>(g); break;
        case EPI_GELU_BF16:  gemm_p<EPI_GELU_BF16><<<grid, blk, 0, stream>>>(g); break;
        case EPI_MUL_BF16:   gemm_p<EPI_MUL_BF16><<<grid, blk, 0, stream>>>(g); break;
        case EPI_RES_F32:    gemm_p<EPI_RES_F32><<<grid, blk, 0, stream>>>(g); break;
        case EPI_RESGATE_F32:gemm_p<EPI_RESGATE_F32><<<grid, blk, 0, stream>>>(g); break;
      }
    } else {
      g.Bp = wf32;
      switch (epi) {
        case EPI_F32:        gemm_rs<EPI_F32><<<grid, blk, 0, stream>>>(g); break;
        case EPI_GELU_BF16:  gemm_rs<EPI_GELU_BF16><<<grid, blk, 0, stream>>>(g); break;
        case EPI_MUL_BF16:   gemm_rs<EPI_MUL_BF16><<<grid, blk, 0, stream>>>(g); break;
        case EPI_RES_F32:    gemm_rs<EPI_RES_F32><<<grid, blk, 0, stream>>>(g); break;
        case EPI_RESGATE_F32:gemm_rs<EPI_RESGATE_F32><<<grid, blk, 0, stream>>>(g); break;
      }
    }
  };

  // 1) hp = rms(x_prefix)*(1+p_ln1_w)
  rms_scale_2048<<<4096, 256, 0, stream>>>(x_prefix, p_ln1_w, hp);
  // 2) mod1 ; hs = ada_norm(x_suffix)
  ada_mod_k<<<dim3(12, 8), 256, 0, stream>>>(cond, s_ada1_w, s_ada1_b, mod1);
  ada_norm_k<<<512, 256, 0, stream>>>(x_suffix, mod1, hs);

  // 3) prefix QKV fused: qkv[b, 0..511, 0..2559] = hp @ [p_q;p_k;p_v]^T  (8p)
  if (conv) {
    GemmArgs g = mkG(hp, 512ll * 2048, 2048, w_pqkv, 0, 2048, 1,
                     qkv, (ll)Tt * 2560, 0, 1, 2560, 512, 2560, 2048);
    gemm_8p<EPI_F32, 128><<<dim3(2, 20, 8), 512, 0, stream>>>(g);
  } else {
    launchW(EPI_F32, mkG(hp, 512ll * 2048, 2048, nullptr, 0, 2048, 1,
                         qkv, (ll)Tt * 2560, 0, 1, 2560, 512, 2048, 2048),
            p_q, nullptr, dim3(4, 16, 8));
    launchW(EPI_F32, mkG(hp, 512ll * 2048, 2048, nullptr, 0, 2048, 1,
                         qkv + 2048, (ll)Tt * 2560, 0, 1, 2560, 512, 256, 2048),
            p_k, nullptr, dim3(4, 2, 8));
    launchW(EPI_F32, mkG(hp, 512ll * 2048, 2048, nullptr, 0, 2048, 1,
                         qkv + 2304, (ll)Tt * 2560, 0, 1, 2560, 512, 256, 2048),
            p_v, nullptr, dim3(4, 2, 8));
  }
  // 4) suffix QKV fused: qkv[b, 512..575, :] = hs @ [s_q;s_k;s_v]^T  (gemm_p)
  if (conv) {
    GemmArgs g = mkG(hs, 64ll * 1024, 1024, w_sqkv, 0, 1024, 1,
                     qkv + 512ll * 2560, (ll)Tt * 2560, 0, 1, 2560, 64, 2560, 1024);
    gemm_p<EPI_F32><<<dim3(1, 20, 8), blk, 0, stream>>>(g);
  } else {
    launchW(EPI_F32, mkG(hs, 64ll * 1024, 1024, nullptr, 0, 1024, 1,
                         qkv + 512ll * 2560, (ll)Tt * 2560, 0, 1, 2560, 64, 2048, 1024),
            s_q, nullptr, dim3(1, 16, 8));
    launchW(EPI_F32, mkG(hs, 64ll * 1024, 1024, nullptr, 0, 1024, 1,
                         qkv + 512ll * 2560 + 2048, (ll)Tt * 2560, 0, 1, 2560, 64, 256, 1024),
            s_k, nullptr, dim3(1, 2, 8));
    launchW(EPI_F32, mkG(hs, 64ll * 1024, 1024, nullptr, 0, 1024, 1,
                         qkv + 512ll * 2560 + 2304, (ll)Tt * 2560, 0, 1, 2560, 64, 256, 1024),
            s_v, nullptr, dim3(1, 2, 8));
  }
  // 5) RoPE + V transpose
  rope_k<<<8 * Tt, 256, 0, stream>>>(qkv, pos, qb, kb, vT);

  // 6) scores
  {
    GemmArgs g = mkG(qb, (ll)Tt * 256, 256, kb, (ll)Tt * 256, 256, 8,
                     scores, (ll)Tt * Tt, 0, 1, Tt, Tt, Tt, 256);
    g.alpha = SCALEf;
    gemm_p<EPI_SCALE_BF16><<<dim3(5, 5, 64), blk, 0, stream>>>(g);
  }
  // 7) softmax
  softmax_k<<<64 * Tt / 4, 256, 0, stream>>>(scores, mask, probs);
  // 8) attn = probs @ v0
  {
    GemmArgs g = mkG(probs, (ll)Tt * Tt, Tt, vT, 256ll * Tt, Tt, 8,
                     attn, (ll)Tt * 2048, 256, 8, 2048, Tt, 256, Tt);
    gemm_p<EPI_BF16><<<dim3(5, 2, 64), blk, 0, stream>>>(g);
  }
  // 9) res_p = x_prefix + a_p @ p_o^T  (8p)
  {
    GemmArgs g = mkG(attn, (ll)Tt * 2048, 2048, w_po, 0, 2048, 1,
                     res_p, 512ll * 2048, 0, 1, 2048, 512, 2048, 2048);
    g.res = x_prefix; g.sRes = 512ll * 2048;
    if (conv) gemm_8p<EPI_RES_F32, 128><<<dim3(2, 16, 8), 512, 0, stream>>>(g);
    else      launchW(EPI_RES_F32, g, p_o, w_po, dim3(4, 16, 8));
  }
  // 10) res_s = x_suffix + (a_s @ s_o^T) * gate1
  {
    GemmArgs g = mkG(attn + 512ll * 2048, (ll)Tt * 2048, 2048, nullptr, 0, 2048, 1,
                     res_s, 64ll * 1024, 0, 1, 1024, 64, 1024, 2048);
    g.res = x_suffix; g.sRes = 64ll * 1024;
    g.gate = mod1 + 2048; g.sGate = 3072;
    launchW(EPI_RESGATE_F32, g, s_o, w_so, dim3(1, 8, 8));
  }
  // 11) norms for MLP
  rms_scale_2048<<<4096, 256, 0, stream>>>(res_p, p_ln2_w, hbuf);
  ada_mod_k<<<dim3(12, 8), 256, 0, stream>>>(cond, s_ada2_w, s_ada2_b, mod2);
  ada_norm_k<<<512, 256, 0, stream>>>(res_s, mod2, h2);

  // 12) prefix MLP: fused gelu(h@gate^T)*(h@up^T) -> gbuf (8pf); down via 8p
  if (conv) {
    FusedArgs fg{hbuf, 2048, w_pg, w_pu, 2048, gbuf, 16384, 2048};
    gemm_8pf<<<dim3(16, 128, 1), 512, 0, stream>>>(fg);
  } else {
    launchW(EPI_GELU_BF16, mkG(hbuf, 0, 2048, nullptr, 0, 2048, 1,
                               gbuf, 0, 0, 1, 16384, 4096, 16384, 2048),
            p_gate, w_pg, dim3(32, 128, 1));
    GemmArgs g = mkG(hbuf, 0, 2048, nullptr, 0, 2048, 1,
                     gbuf, 0, 0, 1, 16384, 4096, 16384, 2048);
    g.aux = gbuf; g.sAux = 0;
    launchW(EPI_MUL_BF16, g, p_up, w_pu, dim3(32, 128, 1));
  }
  {
    GemmArgs g = mkG(gbuf, 0, 16384, w_pd, 0, 16384, 1,
                     outp, 0, 0, 1, 2048, 4096, 2048, 16384);
    g.res = res_p; g.sRes = 0;
    if (conv) gemm_8p<EPI_RES_F32, 128><<<dim3(16, 16, 1), 512, 0, stream>>>(g);
    else      launchW(EPI_RES_F32, g, p_down, w_pd, dim3(32, 16, 1));
  }
  // 13) suffix MLP with gate2: fused gate+up, then down
  if (conv) {
    FusedArgs fg{h2, 1024, w_sg, w_su, 1024, gbuf_s, 4096, 1024};
    gemm_8pf<<<dim3(2, 32, 1), 512, 0, stream>>>(fg);
  } else {
    launchW(EPI_GELU_BF16, mkG(h2, 0, 1024, nullptr, 0, 1024, 1,
                               gbuf_s, 0, 0, 1, 4096, 512, 4096, 1024),
            s_gate, w_sg, dim3(4, 32, 1));
    GemmArgs g = mkG(h2, 0, 1024, nullptr, 0, 1024, 1,
                     gbuf_s, 0, 0, 1, 4096, 512, 4096, 1024);
    g.aux = gbuf_s; g.sAux = 0;
    launchW(EPI_MUL_BF16, g, s_up, w_su, dim3(4, 32, 1));
  }
  {
    GemmArgs g = mkG(gbuf_s, 64ll * 4096, 4096, nullptr, 0, 4096, 1,
                     outs, 64ll * 1024, 0, 1, 1024, 64, 1024, 4096);
    g.res = res_s; g.sRes = 64ll * 1024;
    g.gate = mod2 + 2048; g.sGate = 3072;
    launchW(EPI_RESGATE_F32, g, s_down, w_sd, dim3(1, 8, 8));
  }
}

// Round 14
// 1813.890 us; speedup vs baseline: 1.0118x; 1.0118x over previous
//
#include <hip/hip_runtime.h>
#include <cstdint>
#include <cstddef>

typedef __bf16 bf;
typedef __attribute__((ext_vector_type(8))) __bf16 bf16x8;
typedef __attribute__((ext_vector_type(4))) float f32x4;
typedef long long ll;

#define DEV __device__ __forceinline__

// ---- problem constants ----
constexpr int Tt = 576;
constexpr int NHh = 8;
constexpr float EPSf = 1e-6f;
constexpr float SCALEf = 0.0625f;          // HD^-0.5 = 1/16
constexpr float LN1E4_OVER_128 = 0.07195578515606394f; // ln(10000)/128

constexpr int EPI_F32 = 0, EPI_SCALE_BF16 = 1, EPI_BF16 = 2, EPI_GELU_BF16 = 3,
              EPI_MUL_BF16 = 4, EPI_RES_F32 = 5, EPI_RESGATE_F32 = 6;

DEV float wsum(float v) {
#pragma unroll
  for (int o = 32; o > 0; o >>= 1) v += __shfl_xor(v, o, 64);
  return v;
}
DEV float wmaxr(float v) {
#pragma unroll
  for (int o = 32; o > 0; o >>= 1) v = fmaxf(v, __shfl_xor(v, o, 64));
  return v;
}
DEV float gelu_tanh(float x) {
  float x3 = x * x * x;
  float t = tanhf(0.7978845608028654f * (x + 0.044715f * x3));
  return 0.5f * x * (1.0f + t);
}

// async global->LDS, 16B per lane, wave-uniform LDS base + lane*16 (m97 pattern)
DEV void gld16(const void* g, void* l) {
  __builtin_amdgcn_global_load_lds(
      (__attribute__((address_space(1))) void*)(g),
      (__attribute__((address_space(3))) void*)(l), 16, 0, 0);
}

// ---------------- small kernels ----------------

// batched fp32->bf16 conversion of all 14 weight matrices (contiguous bf16 dst)
struct CvtArgs {
  const float* src[14];
  ll cum8[15];     // vec8 prefix offsets
  bf* dst;         // contiguous destination base
};

__global__ void f2b_all(CvtArgs a, int totN8) {
  int i = blockIdx.x * 256 + threadIdx.x;
  int stride = gridDim.x * 256;
  for (; i < totN8; i += stride) {
    int s = 0;
#pragma unroll
    for (int j = 1; j < 14; j++) if (i >= a.cum8[j]) s = j;
    const float* sp = a.src[s] + ((ll)i - a.cum8[s]) * 8;
    f32x4 v0 = *(const f32x4*)sp;
    f32x4 v1 = *(const f32x4*)(sp + 4);
    bf16x8 w;
    w[0] = (bf)v0[0]; w[1] = (bf)v0[1]; w[2] = (bf)v0[2]; w[3] = (bf)v0[3];
    w[4] = (bf)v1[0]; w[5] = (bf)v1[1]; w[6] = (bf)v1[2]; w[7] = (bf)v1[3];
    ((bf16x8*)a.dst)[i] = w;
  }
}

__global__ void rms_scale_2048(const float* __restrict__ x, const float* __restrict__ w,
                               bf* __restrict__ out) {
  int row = blockIdx.x;
  int tid = threadIdx.x;
  const float* xr = x + (ll)row * 2048;
  f32x4 a = *(const f32x4*)(xr + tid * 4);
  f32x4 b = *(const f32x4*)(xr + 1024 + tid * 4);
  float ss = a[0]*a[0]+a[1]*a[1]+a[2]*a[2]+a[3]*a[3]
           + b[0]*b[0]+b[1]*b[1]+b[2]*b[2]+b[3]*b[3];
  ss = wsum(ss);
  __shared__ float red[4];
  if ((tid & 63) == 0) red[tid >> 6] = ss;
  __syncthreads();
  float tot = red[0] + red[1] + red[2] + red[3];
  float sc = rsqrtf(tot * (1.0f / 2048.0f) + EPSf);
  bf* o = out + (ll)row * 2048;
#pragma unroll
  for (int j = 0; j < 4; j++) {
    int c0 = tid * 4 + j;
    o[c0]        = (bf)(a[j] * sc * (1.0f + w[c0]));
    o[1024 + c0] = (bf)(b[j] * sc * (1.0f + w[1024 + c0]));
  }
}

__global__ void ada_mod_k(const float* __restrict__ cond, const float* __restrict__ w,
                          const float* __restrict__ bias, float* __restrict__ mod) {
  int n = blockIdx.x * 256 + threadIdx.x;
  int b = blockIdx.y;
  const float* c = cond + b * 1024;
  const float* wr = w + (ll)n * 1024;
  float s = 0.f;
  for (int k = 0; k < 1024; k += 4) {
    f32x4 cv = *(const f32x4*)(c + k);
    f32x4 wv = *(const f32x4*)(wr + k);
    s += cv[0]*wv[0] + cv[1]*wv[1] + cv[2]*wv[2] + cv[3]*wv[3];
  }
  mod[b * 3072 + n] = s + bias[n];
}

__global__ void ada_norm_k(const float* __restrict__ x, const float* __restrict__ mod,
                           bf* __restrict__ out) {
  int row = blockIdx.x;
  int b = row >> 6;
  int tid = threadIdx.x;
  const float* xr = x + (ll)row * 1024;
  f32x4 a = *(const f32x4*)(xr + tid * 4);
  float ss = a[0]*a[0] + a[1]*a[1] + a[2]*a[2] + a[3]*a[3];
  ss = wsum(ss);
  __shared__ float red[4];
  if ((tid & 63) == 0) red[tid >> 6] = ss;
  __syncthreads();
  float tot = red[0] + red[1] + red[2] + red[3];
  float sc = rsqrtf(tot * (1.0f / 1024.0f) + EPSf);
  const float* m = mod + b * 3072;
  bf* o = out + (ll)row * 1024;
#pragma unroll
  for (int j = 0; j < 4; j++) {
    int c = tid * 4 + j;
    o[c] = (bf)(a[j] * sc * (1.0f + m[c]) + m[1024 + c]);
  }
}

// RoPE from fused qkv buffer (B,T,2560): q cols 0-2047, k 2048-2303, v 2304-2559
__global__ void rope_k(const float* __restrict__ qkv,
                       const int* __restrict__ pos, bf* __restrict__ qb,
                       bf* __restrict__ kb, bf* __restrict__ vT) {
  int bt = blockIdx.x;
  int b = bt / Tt, t = bt - b * Tt;
  int tid = threadIdx.x;
  float p = (float)pos[bt];
  const float* qr = qkv + (ll)bt * 2560;
#pragma unroll
  for (int j = 0; j < 4; j++) {
    int pi = tid + 256 * j;       // 0..1023
    int h = pi >> 7, d = pi & 127;
    float ang = p * expf((float)d * (-LN1E4_OVER_128));
    float sn = sinf(ang), cs = cosf(ang);
    float x1 = qr[h * 256 + d], x2 = qr[h * 256 + d + 128];
    bf* qo = qb + ((ll)(b * NHh + h) * Tt + t) * 256;
    qo[d]       = (bf)(x1 * cs - x2 * sn);
    qo[d + 128] = (bf)(x2 * cs + x1 * sn);
  }
  const float* kvr = qr + 2048;
  if (tid < 128) {
    int d = tid;
    float ang = p * expf((float)d * (-LN1E4_OVER_128));
    float sn = sinf(ang), cs = cosf(ang);
    float x1 = kvr[d], x2 = kvr[d + 128];
    bf* ko = kb + (ll)bt * 256;
    ko[d]       = (bf)(x1 * cs - x2 * sn);
    ko[d + 128] = (bf)(x2 * cs + x1 * sn);
  } else {
    int d = tid - 128;
    const float* vv = kvr + 256;
    vT[((ll)b * 256 + d) * Tt + t]       = (bf)vv[d];
    vT[((ll)b * 256 + d + 128) * Tt + t] = (bf)vv[d + 128];
  }
}

__global__ void softmax_k(const bf* __restrict__ scores, const float* __restrict__ mask,
                          bf* __restrict__ probs) {
  int rowg = blockIdx.x * 4 + (threadIdx.x >> 6);
  int lane = threadIdx.x & 63;
  int z = rowg / Tt;       // b*NH+h
  int t = rowg - z * Tt;
  int b = z >> 3;
  const bf* s = scores + (ll)rowg * Tt;
  const float* mr = mask + ((ll)b * Tt + t) * Tt;
  float v[9];
#pragma unroll
  for (int j = 0; j < 9; j++) {
    int c = lane + j * 64;
    v[j] = (float)s[c] + mr[c];
  }
  float mx = v[0];
#pragma unroll
  for (int j = 1; j < 9; j++) mx = fmaxf(mx, v[j]);
  mx = wmaxr(mx);
  float sum = 0.f;
#pragma unroll
  for (int j = 0; j < 9; j++) { v[j] = __expf(v[j] - mx); sum += v[j]; }
  sum = wsum(sum);
  float inv = 1.0f / sum;
  bf* pr = probs + (ll)rowg * Tt;
#pragma unroll
  for (int j = 0; j < 9; j++) pr[lane + j * 64] = (bf)(v[j] * inv);
}

// ---------------- GEMM: C = A (bf16, MxK) * B^T ----------------

struct GemmArgs {
  const bf* A; ll sA; int lda;
  const void* Bp; ll sB; int ldb; int zdivB;
  void* C; ll sC; ll sC2; int zdivC; int ldc;
  int M, N, K;
  const float* res; ll sRes;
  const float* gate; ll sGate;
  const bf* aux; ll sAux;
  float alpha;
};

template <int EPI>
DEV void epilogue(const GemmArgs& g, f32x4 (&acc)[4][4], int z, int m0, int n0,
                  int lane, int wr, int wc) {
  const ll coff = (ll)(z / g.zdivC) * g.sC + (ll)(z % g.zdivC) * g.sC2;
  const int r0 = (lane >> 4) * 4;
  const int cc = lane & 15;
#pragma unroll
  for (int m = 0; m < 4; m++) {
#pragma unroll
    for (int n = 0; n < 4; n++) {
      int col = n0 + wc * 64 + n * 16 + cc;
      if (col >= g.N) continue;
#pragma unroll
      for (int r = 0; r < 4; r++) {
        int row = m0 + wr * 64 + m * 16 + r0 + r;
        if (row >= g.M) continue;
        float v = acc[m][n][r];
        ll idx = (ll)row * g.ldc + col;
        if constexpr (EPI == EPI_F32) {
          ((float*)g.C)[coff + idx] = v;
        } else if constexpr (EPI == EPI_SCALE_BF16) {
          ((bf*)g.C)[coff + idx] = (bf)(v * g.alpha);
        } else if constexpr (EPI == EPI_BF16) {
          ((bf*)g.C)[coff + idx] = (bf)v;
        } else if constexpr (EPI == EPI_GELU_BF16) {
          ((bf*)g.C)[coff + idx] = (bf)gelu_tanh(v);
        } else if constexpr (EPI == EPI_MUL_BF16) {
          float a0 = (float)g.aux[(ll)z * g.sAux + idx];
          ((bf*)g.C)[coff + idx] = (bf)(a0 * v);
        } else if constexpr (EPI == EPI_RES_F32) {
          ((float*)g.C)[coff + idx] = g.res[(ll)z * g.sRes + idx] + v;
        } else if constexpr (EPI == EPI_RESGATE_F32) {
          ((float*)g.C)[coff + idx] =
              g.res[(ll)z * g.sRes + idx] + v * g.gate[(ll)z * g.sGate + col];
        }
      }
    }
  }
}

// ======== 8-phase 256xBN GEMM (r12-proven: B staged at p0, A staged at p1,
// 16x16x32 MFMA, T2 both-sides swizzle -> conflict-free 2-way reads) ========
template <int EPI, int BN>
__global__ __launch_bounds__(512) void gemm_8p(GemmArgs g) {
  constexpr int NF = BN / 64;            // B-frags per wave
  constexpr int WN = BN / 4;             // wave col span
  const int z = blockIdx.z;
  const int m0 = blockIdx.x * 256;
  const int n0 = blockIdx.y * BN;
  const int tid = threadIdx.x;
  const int lane = tid & 63;
  const int wv = tid >> 6;               // 0..7
  const int wr = wv >> 2;                // 0..1 (M half)
  const int wc = wv & 3;                 // 0..3 (N quarter)

  const bf* A = g.A + (ll)z * g.sA;
  const bf* B = (const bf*)g.Bp + (ll)(z / g.zdivB) * g.sB;

  __shared__ __align__(16) bf lA[2][256 * 64];
  __shared__ __align__(16) bf lB[2][BN * 64];

  f32x4 acc[8][NF];
  f32x4 zero = {0.f, 0.f, 0.f, 0.f};
#pragma unroll
  for (int m = 0; m < 8; m++)
#pragma unroll
    for (int n = 0; n < NF; n++) acc[m][n] = zero;

  const int lrow = lane >> 3;                  // 0..7
  const int lsrc = ((lane & 7) ^ lrow) * 8;    // T2 swizzled source col

  auto stage128 = [&](const bf* src, int ld, int grow0, bf* lds) {
#pragma unroll
    for (int i = 0; i < 2; i++) {
      int chunk = wv * 2 + i;                  // wave-uniform base
      gld16(src + (ll)(grow0 + chunk * 8 + lrow) * ld + lsrc, lds + chunk * 512);
    }
  };

  const int NT = g.K >> 6;
  stage128(B, g.ldb, n0, &lB[0][0]);
  if (BN == 256) stage128(B, g.ldb, n0 + 128, &lB[0][128 * 64]);
  stage128(A, g.lda, m0, &lA[0][0]);
  stage128(A, g.lda, m0 + 128, &lA[0][128 * 64]);
  asm volatile("s_waitcnt vmcnt(0)" ::: "memory");
  __builtin_amdgcn_s_barrier();

  for (int t = 0; t < NT; ++t) {
    const int c = t & 1;
    const int nx = (t + 1 < NT) ? t + 1 : t;
    const ll kkn = (ll)nx * 64;
    bf16x8 bv[NF][2];
#pragma unroll
    for (int p = 0; p < 4; ++p) {
      if (p == 0) {
#pragma unroll
        for (int n = 0; n < NF; ++n)
#pragma unroll
          for (int kb = 0; kb < 2; ++kb) {
            int row = wc * WN + n * 16 + (lane & 15);
            int ko = kb * 32 + (lane >> 4) * 8;
            bv[n][kb] = *(const bf16x8*)&lB[c][row * 64 + (ko ^ ((row & 7) * 8))];
          }
      }
      bf16x8 af[2][2];
#pragma unroll
      for (int ml = 0; ml < 2; ++ml)
#pragma unroll
        for (int kb = 0; kb < 2; ++kb) {
          int row = wr * 128 + (2 * p + ml) * 16 + (lane & 15);
          int ko = kb * 32 + (lane >> 4) * 8;
          af[ml][kb] = *(const bf16x8*)&lA[c][row * 64 + (ko ^ ((row & 7) * 8))];
        }
      if (p == 0) {                              // B(t+1) at p0
        stage128(B + kkn, g.ldb, n0, &lB[1 - c][0]);
        if (BN == 256) stage128(B + kkn, g.ldb, n0 + 128, &lB[1 - c][128 * 64]);
      } else if (p == 1) {                       // A(t+1) at p1
        stage128(A + kkn, g.lda, m0, &lA[1 - c][0]);
        stage128(A + kkn, g.lda, m0 + 128, &lA[1 - c][128 * 64]);
      }
      __builtin_amdgcn_s_barrier();
      asm volatile("s_waitcnt lgkmcnt(0)" ::: "memory");
      __builtin_amdgcn_s_setprio(1);
#pragma unroll
      for (int kb = 0; kb < 2; ++kb)
#pragma unroll
        for (int ml = 0; ml < 2; ++ml)
#pragma unroll
          for (int n = 0; n < NF; ++n)
            acc[2 * p + ml][n] = __builtin_amdgcn_mfma_f32_16x16x32_bf16(
                af[ml][kb], bv[n][kb], acc[2 * p + ml][n], 0, 0, 0);
      __builtin_amdgcn_s_setprio(0);
      if (p == 3) asm volatile("s_waitcnt vmcnt(0)" ::: "memory");
      __builtin_amdgcn_s_barrier();
    }
  }

  const ll coff = (ll)(z / g.zdivC) * g.sC + (ll)(z % g.zdivC) * g.sC2;
  const int r0 = (lane >> 4) * 4;
  const int cc = lane & 15;
#pragma unroll
  for (int m = 0; m < 8; m++) {
#pragma unroll
    for (int n = 0; n < NF; n++) {
      int col = n0 + wc * WN + n * 16 + cc;
#pragma unroll
      for (int r = 0; r < 4; r++) {
        int row = m0 + wr * 128 + m * 16 + r0 + r;
        float v = acc[m][n][r];
        ll idx = (ll)row * g.ldc + col;
        if constexpr (EPI == EPI_F32) {
          ((float*)g.C)[coff + idx] = v;
        } else if constexpr (EPI == EPI_GELU_BF16) {
          ((bf*)g.C)[coff + idx] = (bf)gelu_tanh(v);
        } else if constexpr (EPI == EPI_MUL_BF16) {
          float a0 = (float)g.aux[(ll)z * g.sAux + idx];
          ((bf*)g.C)[coff + idx] = (bf)(a0 * v);
        } else if constexpr (EPI == EPI_RES_F32) {
          ((float*)g.C)[coff + idx] = g.res[(ll)z * g.sRes + idx] + v;
        }
      }
    }
  }
}

// ======== fused dual-B 8-phase MLP kernel (r12-proven: B1/B2 at p0, A at p1) ========
// C = gelu(A@B1^T) * (A@B2^T). BM=256, BN=128. LDS = 64 + 32 + 32 = 128 KB.
struct FusedArgs {
  const bf* A; int lda;
  const bf* B1; const bf* B2; int ldb;
  bf* C; int ldc;
  int K;
};

__global__ __launch_bounds__(512) void gemm_8pf(FusedArgs g) {
  const int m0 = blockIdx.x * 256;
  const int n0 = blockIdx.y * 128;
  const int tid = threadIdx.x;
  const int lane = tid & 63;
  const int wv = tid >> 6;
  const int wr = wv >> 2;
  const int wc = wv & 3;

  __shared__ __align__(16) bf lA[2][256 * 64];
  __shared__ __align__(16) bf lB1[2][128 * 64];
  __shared__ __align__(16) bf lB2[2][128 * 64];

  f32x4 acc1[8][2], acc2[8][2];
  f32x4 zero = {0.f, 0.f, 0.f, 0.f};
#pragma unroll
  for (int m = 0; m < 8; m++)
#pragma unroll
    for (int n = 0; n < 2; n++) { acc1[m][n] = zero; acc2[m][n] = zero; }

  const int lrow = lane >> 3;
  const int lsrc = ((lane & 7) ^ lrow) * 8;

  auto stage128 = [&](const bf* src, int ld, int grow0, bf* lds) {
#pragma unroll
    for (int i = 0; i < 2; i++) {
      int chunk = wv * 2 + i;
      gld16(src + (ll)(grow0 + chunk * 8 + lrow) * ld + lsrc, lds + chunk * 512);
    }
  };

  const int NT = g.K >> 6;
  stage128(g.B1, g.ldb, n0, &lB1[0][0]);
  stage128(g.B2, g.ldb, n0, &lB2[0][0]);
  stage128(g.A, g.lda, m0, &lA[0][0]);
  stage128(g.A, g.lda, m0 + 128, &lA[0][128 * 64]);
  asm volatile("s_waitcnt vmcnt(0)" ::: "memory");
  __builtin_amdgcn_s_barrier();

  for (int t = 0; t < NT; ++t) {
    const int c = t & 1;
    const int nx = (t + 1 < NT) ? t + 1 : t;
    const ll kkn = (ll)nx * 64;
    bf16x8 b1v[2][2], b2v[2][2];
#pragma unroll
    for (int p = 0; p < 4; ++p) {
      if (p == 0) {
#pragma unroll
        for (int n = 0; n < 2; ++n)
#pragma unroll
          for (int kb = 0; kb < 2; ++kb) {
            int row = wc * 32 + n * 16 + (lane & 15);
            int ko = kb * 32 + (lane >> 4) * 8;
            int sw = row * 64 + (ko ^ ((row & 7) * 8));
            b1v[n][kb] = *(const bf16x8*)&lB1[c][sw];
            b2v[n][kb] = *(const bf16x8*)&lB2[c][sw];
          }
      }
      bf16x8 af[2][2];
#pragma unroll
      for (int ml = 0; ml < 2; ++ml)
#pragma unroll
        for (int kb = 0; kb < 2; ++kb) {
          int row = wr * 128 + (2 * p + ml) * 16 + (lane & 15);
          int ko = kb * 32 + (lane >> 4) * 8;
          af[ml][kb] = *(const bf16x8*)&lA[c][row * 64 + (ko ^ ((row & 7) * 8))];
        }
      if (p == 0) {                              // B1,B2(t+1) at p0
        stage128(g.B1 + kkn, g.ldb, n0, &lB1[1 - c][0]);
        stage128(g.B2 + kkn, g.ldb, n0, &lB2[1 - c][0]);
      } else if (p == 1) {                       // A(t+1) at p1
        stage128(g.A + kkn, g.lda, m0, &lA[1 - c][0]);
        stage128(g.A + kkn, g.lda, m0 + 128, &lA[1 - c][128 * 64]);
      }
      __builtin_amdgcn_s_barrier();
      asm volatile("s_waitcnt lgkmcnt(0)" ::: "memory");
      __builtin_amdgcn_s_setprio(1);
#pragma unroll
      for (int kb = 0; kb < 2; ++kb)
#pragma unroll
        for (int ml = 0; ml < 2; ++ml)
#pragma unroll
          for (int n = 0; n < 2; ++n) {
            acc1[2 * p + ml][n] = __builtin_amdgcn_mfma_f32_16x16x32_bf16(
                af[ml][kb], b1v[n][kb], acc1[2 * p + ml][n], 0, 0, 0);
            acc2[2 * p + ml][n] = __builtin_amdgcn_mfma_f32_16x16x32_bf16(
                af[ml][kb], b2v[n][kb], acc2[2 * p + ml][n], 0, 0, 0);
          }
      __builtin_amdgcn_s_setprio(0);
      if (p == 3) asm volatile("s_waitcnt vmcnt(0)" ::: "memory");
      __builtin_amdgcn_s_barrier();
    }
  }

  const int r0 = (lane >> 4) * 4;
  const int cc = lane & 15;
#pragma unroll
  for (int m = 0; m < 8; m++) {
#pragma unroll
    for (int n = 0; n < 2; n++) {
      int col = n0 + wc * 32 + n * 16 + cc;
#pragma unroll
      for (int r = 0; r < 4; r++) {
        int row = m0 + wr * 128 + m * 16 + r0 + r;
        g.C[(ll)row * g.ldc + col] =
            (bf)(gelu_tanh(acc1[m][n][r]) * acc2[m][n][r]);
      }
    }
  }
}

// Pipelined 128x128 GEMM (proven) for small/irregular shapes.
template <int EPI>
__global__ __launch_bounds__(256) void gemm_p(GemmArgs g) {
  const int z = blockIdx.z;
  const int m0 = blockIdx.x * 128;
  const int n0 = blockIdx.y * 128;
  const int tid = threadIdx.x;
  const int lane = tid & 63;
  const int wid = tid >> 6;
  const int wr = wid >> 1, wc = wid & 1;

  const bf* A = g.A + (ll)z * g.sA;
  const bf* B = (const bf*)g.Bp + (ll)(z / g.zdivB) * g.sB;

  __shared__ __align__(16) bf lA[2][128 * 64];
  __shared__ __align__(16) bf lB[2][128 * 64];

  f32x4 acc[4][4];
  f32x4 zero = {0.f, 0.f, 0.f, 0.f};
#pragma unroll
  for (int m = 0; m < 4; m++)
#pragma unroll
    for (int n = 0; n < 4; n++) acc[m][n] = zero;

  const int lrow = lane >> 3;
  const int lsrc = ((lane & 7) ^ lrow) * 8;

  auto stage = [&](int kt, int bsel) {
    const ll kk = (ll)kt * 64;
#pragma unroll
    for (int i = 0; i < 4; i++) {
      int rr = wid * 32 + i * 8;
      int ra = m0 + rr + lrow; if (ra > g.M - 1) ra = g.M - 1;
      gld16(A + (ll)ra * g.lda + kk + lsrc, &lA[bsel][rr * 64]);
      int rb = n0 + rr + lrow; if (rb > g.N - 1) rb = g.N - 1;
      gld16(B + (ll)rb * g.ldb + kk + lsrc, &lB[bsel][rr * 64]);
    }
  };

  const int nt = g.K >> 6;
  stage(0, 0);
  stage(nt > 1 ? 1 : 0, 1);

  for (int t = 0; t < nt; ++t) {
    const int cur = t & 1;
    asm volatile("s_waitcnt vmcnt(8)" ::: "memory");
    __builtin_amdgcn_s_barrier();
    asm volatile("" ::: "memory");
#pragma unroll
    for (int kb = 0; kb < 2; kb++) {
      const int ko = kb * 32 + (lane >> 4) * 8;
      bf16x8 af[4], bv[4];
#pragma unroll
      for (int m = 0; m < 4; m++) {
        int row = wr * 64 + m * 16 + (lane & 15);
        af[m] = *(const bf16x8*)&lA[cur][row * 64 + (ko ^ ((row & 7) * 8))];
      }
#pragma unroll
      for (int n = 0; n < 4; n++) {
        int row = wc * 64 + n * 16 + (lane & 15);
        bv[n] = *(const bf16x8*)&lB[cur][row * 64 + (ko ^ ((row & 7) * 8))];
      }
      __builtin_amdgcn_s_setprio(1);
#pragma unroll
      for (int m = 0; m < 4; m++)
#pragma unroll
        for (int n = 0; n < 4; n++)
          acc[m][n] = __builtin_amdgcn_mfma_f32_16x16x32_bf16(af[m], bv[n], acc[m][n], 0, 0, 0);
      __builtin_amdgcn_s_setprio(0);
    }
    asm volatile("" ::: "memory");
    __builtin_amdgcn_s_barrier();
    asm volatile("" ::: "memory");
    int nxt = t + 2; if (nxt > nt - 1) nxt = nt - 1;
    stage(nxt, cur);
  }
  epilogue<EPI>(g, acc, z, m0, n0, lane, wr, wc);
}

// fallback: reg-staged, B fp32 converted in-flight
template <int EPI>
__global__ __launch_bounds__(256) void gemm_rs(GemmArgs g) {
  const int z = blockIdx.z;
  const int m0 = blockIdx.x * 128;
  const int n0 = blockIdx.y * 128;
  const int tid = threadIdx.x;
  const int lane = tid & 63;
  const int wid = tid >> 6;
  const int wr = wid >> 1, wc = wid & 1;

  const bf* A = g.A + (ll)z * g.sA;
  const float* Bf = (const float*)g.Bp + (ll)(z / g.zdivB) * g.sB;

  __shared__ __align__(16) bf lA[128 * 64];
  __shared__ __align__(16) bf lB[128 * 64];

  f32x4 acc[4][4];
  f32x4 zero = {0.f, 0.f, 0.f, 0.f};
#pragma unroll
  for (int m = 0; m < 4; m++)
#pragma unroll
    for (int n = 0; n < 4; n++) acc[m][n] = zero;

  const int srow = tid >> 3;
  const int scol = (tid & 7) * 8;

  for (int kk = 0; kk < g.K; kk += 64) {
#pragma unroll
    for (int i = 0; i < 4; i++) {
      int r = m0 + i * 32 + srow;
      if (r > g.M - 1) r = g.M - 1;
      f32x4 v = *(const f32x4*)(A + (ll)r * g.lda + kk + scol);
      *(f32x4*)&lA[(i * 32 + srow) * 64 + scol] = v;
    }
#pragma unroll
    for (int i = 0; i < 4; i++) {
      int r = n0 + i * 32 + srow;
      if (r > g.N - 1) r = g.N - 1;
      const float* src = Bf + (ll)r * g.ldb + kk + scol;
      f32x4 v0 = *(const f32x4*)(src);
      f32x4 v1 = *(const f32x4*)(src + 4);
      bf16x8 w;
      w[0] = (bf)v0[0]; w[1] = (bf)v0[1]; w[2] = (bf)v0[2]; w[3] = (bf)v0[3];
      w[4] = (bf)v1[0]; w[5] = (bf)v1[1]; w[6] = (bf)v1[2]; w[7] = (bf)v1[3];
      *(bf16x8*)&lB[(i * 32 + srow) * 64 + scol] = w;
    }
    __syncthreads();
#pragma unroll
    for (int kb = 0; kb < 2; kb++) {
      const int ko = kb * 32 + (lane >> 4) * 8;
      bf16x8 af[4], bfv[4];
#pragma unroll
      for (int m = 0; m < 4; m++)
        af[m] = *(const bf16x8*)&lA[(wr * 64 + m * 16 + (lane & 15)) * 64 + ko];
#pragma unroll
      for (int n = 0; n < 4; n++)
        bfv[n] = *(const bf16x8*)&lB[(wc * 64 + n * 16 + (lane & 15)) * 64 + ko];
#pragma unroll
      for (int m = 0; m < 4; m++)
#pragma unroll
        for (int n = 0; n < 4; n++)
          acc[m][n] = __builtin_amdgcn_mfma_f32_16x16x32_bf16(af[m], bfv[n], acc[m][n], 0, 0, 0);
    }
    __syncthreads();
  }
  epilogue<EPI>(g, acc, z, m0, n0, lane, wr, wc);
}

// ---------------- host ----------------

static GemmArgs mkG(const bf* A, ll sA, int lda, const void* Bp, ll sB, int ldb, int zdivB,
                    void* C, ll sC, ll sC2, int zdivC, int ldc, int M, int N, int K) {
  GemmArgs g{};
  g.A = A; g.sA = sA; g.lda = lda;
  g.Bp = Bp; g.sB = sB; g.ldb = ldb; g.zdivB = zdivB;
  g.C = C; g.sC = sC; g.sC2 = sC2; g.zdivC = zdivC; g.ldc = ldc;
  g.M = M; g.N = N; g.K = K;
  g.res = nullptr; g.sRes = 0; g.gate = nullptr; g.sGate = 0; g.aux = nullptr; g.sAux = 0;
  g.alpha = 1.0f;
  return g;
}

extern "C" void kernel_launch(void* const* d_in, const int* in_sizes, int n_in,
                              void* d_out, int out_size, void* d_ws, size_t ws_size,
                              hipStream_t stream) {
  (void)in_sizes; (void)n_in; (void)out_size;
  const float* x_prefix = (const float*)d_in[0];
  const float* x_suffix = (const float*)d_in[1];
  const float* cond     = (const float*)d_in[2];
  const float* mask     = (const float*)d_in[3];
  const float* p_ln1_w  = (const float*)d_in[4];
  const float* p_q      = (const float*)d_in[5];
  const float* p_k      = (const float*)d_in[6];
  const float* p_v      = (const float*)d_in[7];
  const float* p_o      = (const float*)d_in[8];
  const float* p_ln2_w  = (const float*)d_in[9];
  const float* p_gate   = (const float*)d_in[10];
  const float* p_up     = (const float*)d_in[11];
  const float* p_down   = (const float*)d_in[12];
  const float* s_ada1_w = (const float*)d_in[13];
  const float* s_ada1_b = (const float*)d_in[14];
  const float* s_q      = (const float*)d_in[15];
  const float* s_k      = (const float*)d_in[16];
  const float* s_v      = (const float*)d_in[17];
  const float* s_o      = (const float*)d_in[18];
  const float* s_ada2_w = (const float*)d_in[19];
  const float* s_ada2_b = (const float*)d_in[20];
  const float* s_gate   = (const float*)d_in[21];
  const float* s_up     = (const float*)d_in[22];
  const float* s_down   = (const float*)d_in[23];
  const int*   pos      = (const int*)d_in[24];

  char* base = (char*)d_ws;
  size_t off = 0;
  auto alloc = [&](size_t bytes) {
    char* p = base + off;
    off = (off + bytes + 255) & ~(size_t)255;
    return p;
  };
  float* qkv   = (float*)alloc(8ll * Tt * 2560 * 4);   // q|k|v fused; reused as attn (bf16)
  bf* hp     = (bf*)alloc(4096ll * 2048 * 2);          // reused as hbuf
  bf* hs     = (bf*)alloc(512ll * 1024 * 2);           // reused as h2
  float* mod1 = (float*)alloc(8 * 3072 * 4);
  float* mod2 = (float*)alloc(8 * 3072 * 4);
  bf* qb     = (bf*)alloc(64ll * Tt * 256 * 2);
  bf* kb     = (bf*)alloc(8ll * Tt * 256 * 2);
  bf* vT     = (bf*)alloc(8ll * 256 * Tt * 2);
  bf* scores = (bf*)alloc(64ll * Tt * Tt * 2);         // softmax in-place
  float* res_p = (float*)alloc(8ll * 512 * 2048 * 4);
  float* res_s = (float*)alloc(8ll * 64 * 1024 * 4);
  bf* gbuf   = (bf*)alloc(4096ll * 16384 * 2);

  bf* attn   = (bf*)qkv;
  bf* hbuf   = hp;
  bf* h2     = hs;
  bf* probs  = scores;
  bf* gbuf_s = gbuf;

  // Converted bf16 weights: 14 contiguous 256B-aligned segments (one contiguous
  // dst area). [0..2] and [7..9] form the combined QKV matrices (2560 x K).
  struct WEnt { const float* src; bf* dst; ll n; };
  WEnt went[14] = {
    {p_q,    nullptr, 2048ll * 2048}, {p_k,    nullptr, 256ll * 2048},
    {p_v,    nullptr, 256ll * 2048},  {p_o,    nullptr, 2048ll * 2048},
    {p_gate, nullptr, 16384ll * 2048},{p_up,   nullptr, 16384ll * 2048},
    {p_down, nullptr, 2048ll * 16384},{s_q,    nullptr, 2048ll * 1024},
    {s_k,    nullptr, 256ll * 1024},  {s_v,    nullptr, 256ll * 1024},
    {s_o,    nullptr, 1024ll * 2048}, {s_gate, nullptr, 4096ll * 1024},
    {s_up,   nullptr, 4096ll * 1024}, {s_down, nullptr, 1024ll * 4096},
  };
  for (int i = 0; i < 14; i++) went[i].dst = (bf*)alloc((size_t)went[i].n * 2);
  const bool conv = (off <= ws_size);

  float* outp = (float*)d_out;
  float* outs = outp + 8ll * 512 * 2048;

  dim3 blk(256);

  if (conv) {
    CvtArgs ca{};
    ll c = 0;
    for (int i = 0; i < 14; i++) { ca.src[i] = went[i].src; ca.cum8[i] = c; c += went[i].n / 8; }
    ca.cum8[14] = c;
    ca.dst = went[0].dst;
    f2b_all<<<2048, 256, 0, stream>>>(ca, (int)c);
  }
  const bf* w_pqkv = went[0].dst;                 // combined 2560x2048
  const bf* w_po = went[3].dst, *w_pg = went[4].dst, *w_pu = went[5].dst,
          *w_pd = went[6].dst;
  const bf* w_sqkv = went[7].dst;                 // combined 2560x1024
  const bf* w_so = went[10].dst, *w_sg = went[11].dst,
          *w_su = went[12].dst, *w_sd = went[13].dst;

  auto launchW = [&](int epi, GemmArgs g, const float* wf32, const bf* wbf,
                     dim3 grid) {
    if (conv) {
      g.Bp = wbf;
      switch (epi) {
        case EPI_F32:        gemm_p<EPI_F32><<<grid, blk, 0, stream>>>(g); break;
        case EPI_GELU_BF16:  gemm_p<EPI_GELU_BF16><<<grid, blk, 0, stream>>>(g); break;
        case EPI_MUL_BF16:   gemm_p<EPI_MUL_BF16><<<grid, blk, 0, stream>>>(g); break;
        case EPI_RES_F32:    gemm_p<EPI_RES_F32><<<grid, blk, 0, stream>>>(g); break;
        case EPI_RESGATE_F32:gemm_p<EPI_RESGATE_F32><<<grid, blk, 0, stream>>>(g); break;
      }
    } else {
      g.Bp = wf32;
      switch (epi) {
        case EPI_F32:        gemm_rs<EPI_F32><<<grid, blk, 0, stream>>>(g); break;
        case EPI_GELU_BF16:  gemm_rs<EPI_GELU_BF16><<<grid, blk, 0, stream>>>(g); break;
        case EPI_MUL_BF16:   gemm_rs<EPI_MUL_BF16><<<grid, blk, 0, stream>>>(g); break;
        case EPI_RES_F32:    gemm_rs<EPI_RES_F32><<<grid, blk, 0, stream>>>(g); break;
        case EPI_RESGATE_F32:gemm_rs<EPI_RESGATE_F32><<<grid, blk, 0, stream>>>(g); break;
      }
    }
  };

  // 1) hp = rms(x_prefix)*(1+p_ln1_w)
  rms_scale_2048<<<4096, 256, 0, stream>>>(x_prefix, p_ln1_w, hp);
  // 2) mod1 ; hs = ada_norm(x_suffix)
  ada_mod_k<<<dim3(12, 8), 256, 0, stream>>>(cond, s_ada1_w, s_ada1_b, mod1);
  ada_norm_k<<<512, 256, 0, stream>>>(x_suffix, mod1, hs);

  // 3) prefix QKV fused: qkv[b, 0..511, 0..2559] = hp @ [p_q;p_k;p_v]^T  (8p)
  if (conv) {
    GemmArgs g = mkG(hp, 512ll * 2048, 2048, w_pqkv, 0, 2048, 1,
                     qkv, (ll)Tt * 2560, 0, 1, 2560, 512, 2560, 2048);
    gemm_8p<EPI_F32, 128><<<dim3(2, 20, 8), 512, 0, stream>>>(g);
  } else {
    launchW(EPI_F32, mkG(hp, 512ll * 2048, 2048, nullptr, 0, 2048, 1,
                         qkv, (ll)Tt * 2560, 0, 1, 2560, 512, 2048, 2048),
            p_q, nullptr, dim3(4, 16, 8));
    launchW(EPI_F32, mkG(hp, 512ll * 2048, 2048, nullptr, 0, 2048, 1,
                         qkv + 2048, (ll)Tt * 2560, 0, 1, 2560, 512, 256, 2048),
            p_k, nullptr, dim3(4, 2, 8));
    launchW(EPI_F32, mkG(hp, 512ll * 2048, 2048, nullptr, 0, 2048, 1,
                         qkv + 2304, (ll)Tt * 2560, 0, 1, 2560, 512, 256, 2048),
            p_v, nullptr, dim3(4, 2, 8));
  }
  // 4) suffix QKV fused: qkv[b, 512..575, :] = hs @ [s_q;s_k;s_v]^T  (gemm_p)
  if (conv) {
    GemmArgs g = mkG(hs, 64ll * 1024, 1024, w_sqkv, 0, 1024, 1,
                     qkv + 512ll * 2560, (ll)Tt * 2560, 0, 1, 2560, 64, 2560, 1024);
    gemm_p<EPI_F32><<<dim3(1, 20, 8), blk, 0, stream>>>(g);
  } else {
    launchW(EPI_F32, mkG(hs, 64ll * 1024, 1024, nullptr, 0, 1024, 1,
                         qkv + 512ll * 2560, (ll)Tt * 2560, 0, 1, 2560, 64, 2048, 1024),
            s_q, nullptr, dim3(1, 16, 8));
    launchW(EPI_F32, mkG(hs, 64ll * 1024, 1024, nullptr, 0, 1024, 1,
                         qkv + 512ll * 2560 + 2048, (ll)Tt * 2560, 0, 1, 2560, 64, 256, 1024),
            s_k, nullptr, dim3(1, 2, 8));
    launchW(EPI_F32, mkG(hs, 64ll * 1024, 1024, nullptr, 0, 1024, 1,
                         qkv + 512ll * 2560 + 2304, (ll)Tt * 2560, 0, 1, 2560, 64, 256, 1024),
            s_v, nullptr, dim3(1, 2, 8));
  }
  // 5) RoPE + V transpose
  rope_k<<<8 * Tt, 256, 0, stream>>>(qkv, pos, qb, kb, vT);

  // 6) scores
  {
    GemmArgs g = mkG(qb, (ll)Tt * 256, 256, kb, (ll)Tt * 256, 256, 8,
                     scores, (ll)Tt * Tt, 0, 1, Tt, Tt, Tt, 256);
    g.alpha = SCALEf;
    gemm_p<EPI_SCALE_BF16><<<dim3(5, 5, 64), blk, 0, stream>>>(g);
  }
  // 7) softmax
  softmax_k<<<64 * Tt / 4, 256, 0, stream>>>(scores, mask, probs);
  // 8) attn = probs @ v0
  {
    GemmArgs g = mkG(probs, (ll)Tt * Tt, Tt, vT, 256ll * Tt, Tt, 8,
                     attn, (ll)Tt * 2048, 256, 8, 2048, Tt, 256, Tt);
    gemm_p<EPI_BF16><<<dim3(5, 2, 64), blk, 0, stream>>>(g);
  }
  // 9) res_p = x_prefix + a_p @ p_o^T  (8p)
  {
    GemmArgs g = mkG(attn, (ll)Tt * 2048, 2048, w_po, 0, 2048, 1,
                     res_p, 512ll * 2048, 0, 1, 2048, 512, 2048, 2048);
    g.res = x_prefix; g.sRes = 512ll * 2048;
    if (conv) gemm_8p<EPI_RES_F32, 128><<<dim3(2, 16, 8), 512, 0, stream>>>(g);
    else      launchW(EPI_RES_F32, g, p_o, w_po, dim3(4, 16, 8));
  }
  // 10) res_s = x_suffix + (a_s @ s_o^T) * gate1
  {
    GemmArgs g = mkG(attn + 512ll * 2048, (ll)Tt * 2048, 2048, nullptr, 0, 2048, 1,
                     res_s, 64ll * 1024, 0, 1, 1024, 64, 1024, 2048);
    g.res = x_suffix; g.sRes = 64ll * 1024;
    g.gate = mod1 + 2048; g.sGate = 3072;
    launchW(EPI_RESGATE_F32, g, s_o, w_so, dim3(1, 8, 8));
  }
  // 11) norms for MLP
  rms_scale_2048<<<4096, 256, 0, stream>>>(res_p, p_ln2_w, hbuf);
  ada_mod_k<<<dim3(12, 8), 256, 0, stream>>>(cond, s_ada2_w, s_ada2_b, mod2);
  ada_norm_k<<<512, 256, 0, stream>>>(res_s, mod2, h2);

  // 12) prefix MLP: fused gelu(h@gate^T)*(h@up^T) -> gbuf (8pf); down via 8p
  if (conv) {
    FusedArgs fg{hbuf, 2048, w_pg, w_pu, 2048, gbuf, 16384, 2048};
    gemm_8pf<<<dim3(16, 128, 1), 512, 0, stream>>>(fg);
  } else {
    launchW(EPI_GELU_BF16, mkG(hbuf, 0, 2048, nullptr, 0, 2048, 1,
                               gbuf, 0, 0, 1, 16384, 4096, 16384, 2048),
            p_gate, w_pg, dim3(32, 128, 1));
    GemmArgs g = mkG(hbuf, 0, 2048, nullptr, 0, 2048, 1,
                     gbuf, 0, 0, 1, 16384, 4096, 16384, 2048);
    g.aux = gbuf; g.sAux = 0;
    launchW(EPI_MUL_BF16, g, p_up, w_pu, dim3(32, 128, 1));
  }
  {
    GemmArgs g = mkG(gbuf, 0, 16384, w_pd, 0, 16384, 1,
                     outp, 0, 0, 1, 2048, 4096, 2048, 16384);
    g.res = res_p; g.sRes = 0;
    if (conv) gemm_8p<EPI_RES_F32, 128><<<dim3(16, 16, 1), 512, 0, stream>>>(g);
    else      launchW(EPI_RES_F32, g, p_down, w_pd, dim3(32, 16, 1));
  }
  // 13) suffix MLP with gate2: fused gate+up, then down
  if (conv) {
    FusedArgs fg{h2, 1024, w_sg, w_su, 1024, gbuf_s, 4096, 1024};
    gemm_8pf<<<dim3(2, 32, 1), 512, 0, stream>>>(fg);
  } else {
    launchW(EPI_GELU_BF16, mkG(h2, 0, 1024, nullptr, 0, 1024, 1,
                               gbuf_s, 0, 0, 1, 4096, 512, 4096, 1024),
            s_gate, w_sg, dim3(4, 32, 1));
    GemmArgs g = mkG(h2, 0, 1024, nullptr, 0, 1024, 1,
                     gbuf_s, 0, 0, 1, 4096, 512, 4096, 1024);
    g.aux = gbuf_s; g.sAux = 0;
    launchW(EPI_MUL_BF16, g, s_up, w_su, dim3(4, 32, 1));
  }
  {
    GemmArgs g = mkG(gbuf_s, 64ll * 4096, 4096, nullptr, 0, 4096, 1,
                     outs, 64ll * 1024, 0, 1, 1024, 64, 1024, 4096);
    g.res = res_s; g.sRes = 64ll * 1024;
    g.gate = mod2 + 2048; g.sGate = 3072;
    launchW(EPI_RESGATE_F32, g, s_down, w_sd, dim3(1, 8, 8));
  }
}